// Round 12
// baseline (151.056 us; speedup 1.0000x reference)
//
#include <hip/hip_runtime.h>

// B=8, H=W=128, Cin=128, Cout=256, 3x3 stride2 pad1 -> OH=OW=64.
// Implicit GEMM: M=32768, N=256, K=1152 (9 taps x 128).
// d_out (f32): out_feats[32768*256] | out_coords[32768*3] | alpha[1]
// R19: BARRIER-FREE tap loop. B weights stored FRAGMENT-MAJOR in Bw2
//      (addr = tap*32K + seg*4K + n32*512 + lane*8 holds lane's 8B MFMA
//      fragment) and loaded global->REGISTER (coalesced 512B/wave/fragment-
//      block), double-buffered in named regs bA/bB across fully-unrolled taps.
//      No B LDS, no per-tap barriers: waves free-run after the band sync.
//      A-band (48KB LDS, 4-bit swizzle, register pad predicate) = R16 verbatim.

#define OUT_FEATS_ELEMS (32768 * 256)
#define OUT_COORDS_OFF  OUT_FEATS_ELEMS
#define ALPHA_OFF       (OUT_FEATS_ELEMS + 32768 * 3)

#define BW2_BYTES  (9 * 8 * 4096)            // 294,912 B fragment-major weights

typedef float v16f __attribute__((ext_vector_type(16)));

__device__ __forceinline__ unsigned pk4fp8(float a, float b, float c, float d) {
    unsigned u = 0;
    u = __builtin_amdgcn_cvt_pk_fp8_f32(a, b, u, false);  // bytes 0,1
    u = __builtin_amdgcn_cvt_pk_fp8_f32(c, d, u, true);   // bytes 2,3
    return u;
}

// ---- weight prep: FRAGMENT-MAJOR fp8 weights + coords + alpha ----
// el = ((tap*8+seg)*8+n32)*64 + hh*32 + l31  (36,864 elements, 8B each):
//   Bw2[el*8 .. +8) = fp8 of w[tap*128 + seg*16 + hh*8 + q][n32*32 + l31], q=0..7
__global__ void wprep_kernel(const float* __restrict__ w,
                             const float* __restrict__ alpha,
                             unsigned char* __restrict__ Bw2,
                             float* __restrict__ out) {
    int cid = blockIdx.x * 256 + threadIdx.x;     // 0..36863
    if (cid < 32768) {                            // coords
        int b = cid >> 12, iy = (cid >> 6) & 63, ix = cid & 63;
        float* c = out + OUT_COORDS_OFF + (size_t)cid * 3;
        c[0] = (float)b; c[1] = (float)iy; c[2] = (float)ix;
        if (cid == 0) out[ALPHA_OFF] = alpha[0];
    }
    {
        const int l31 = cid & 31;
        const int hh  = (cid >> 5) & 1;
        const int n32 = (cid >> 6) & 7;
        const int seg = (cid >> 9) & 7;
        const int tap = cid >> 12;                // 0..8
        const int n   = (n32 << 5) + l31;
        const int kb  = (tap << 7) + (seg << 4) + (hh << 3);
        float f[8];
#pragma unroll
        for (int q = 0; q < 8; ++q)
            f[q] = w[(size_t)(kb + q) * 256 + n];
        uint2 r;
        r.x = pk4fp8(f[0], f[1], f[2], f[3]);
        r.y = pk4fp8(f[4], f[5], f[6], f[7]);
        *(uint2*)(Bw2 + (size_t)cid * 8) = r;
    }
}

// ---- coords for fallback path ----
__global__ void coords_alpha_kernel(float* __restrict__ out, const float* __restrict__ alpha) {
    int i = blockIdx.x * 256 + threadIdx.x;
    int b = i >> 12, iy = (i >> 6) & 63, ix = i & 63;
    float* c = out + OUT_COORDS_OFF + (size_t)i * 3;
    c[0] = (float)b; c[1] = (float)iy; c[2] = (float)ix;
    if (i == 0) out[ALPHA_OFF] = alpha[0];
}

// ---- fused conv GEMM: LDS A-band only (48KB), B fragment loads to registers,
//      barrier-free 9-tap loop ----
// Aband: [r 0..2][nx 0..127][128B]. key4=((nx+1)>>1)&15. logical chunk c half h
//   stored at phys chunk c^(key4&7), half h^(key4>>3). r = ny - (2*iy - 1).
//   nx=-1 via register predicate (a0=0). Row r=0 zeroed when iy==0.
__global__ __launch_bounds__(512, 4) void gemm_conv_kernel(
    const float* __restrict__ feats,         // fp32 [B*128*128][128]
    const unsigned char* __restrict__ Bw2,   // fragment-major fp8 weights (288KB)
    float* __restrict__ out)                 // [32768][256]
{
    __shared__ unsigned char Aband[3 * 128 * 128];   // 49,152 B (total LDS)

    const int tid  = threadIdx.x;
    const int bid  = blockIdx.x;             // 0..511
    // XCD-aware: XCD (bid&7) owns batch bb=(bid&7).
    const int my   = ((bid & 7) << 6) + ((bid >> 3) & 63);   // 0..511
    const int m0   = my << 6;
    const int bb   = my >> 6;                // == bid & 7
    const int iy   = my & 63;                // this block's single output row

    const int lane = tid & 63, wave = tid >> 6;  // wave 0..7
    const int wm   = (wave >> 2) << 5;       // 0 / 32   (m within tile)
    const int wn   = (wave & 3) << 6;        // 0 / 64 / 128 / 192
    const int l31  = lane & 31;
    const int hh   = lane >> 5;              // k-half select

    // ---- B fragment base: wave (wn) + lane fixed; tap/seg/j vary ----
    const unsigned char* bbase = Bw2 + ((size_t)(wn >> 5) << 9) + ((size_t)lane << 3);

    long long bA[16], bB[16];                // [j*8+seg] fragment double-buffer
#define LOADB(T, BUF)                                                          \
    _Pragma("unroll")                                                          \
    for (int s = 0; s < 16; ++s)                                               \
        BUF[s] = *(const long long*)(bbase + (T) * 32768 + (s & 7) * 4096 + (s >> 3) * 512);

    // ---- band fill: 3 input rows (ny = 2*iy-1 .. 2*iy+1), fp32 -> fp8 ----
    const int ny0 = (iy << 1) - 1;
    auto issueRow = [&](int r, float4* f) {
        const int ny = ny0 + r;
#pragma unroll
        for (int it = 0; it < 8; ++it) {
            const int idx = (it << 9) + tid;      // 0..4095
            const int nx  = idx >> 5;
            const int c4  = (idx & 31) << 2;      // float index 0..124 step 4
            f[it] = *(const float4*)(feats +
                ((((size_t)(bb << 14) + ny * 128 + nx)) << 7) + c4);
        }
    };
    auto writeRow = [&](int r, const float4* f) {
#pragma unroll
        for (int it = 0; it < 8; ++it) {
            const int idx = (it << 9) + tid;
            const int nx  = idx >> 5;
            const int c4  = (idx & 31) << 2;
            const unsigned u = pk4fp8(f[it].x, f[it].y, f[it].z, f[it].w);
            const int key4 = ((nx + 1) >> 1) & 15;
            const int boff = ((r * 128 + nx) << 7)
                + (((c4 >> 4) ^ (key4 & 7)) << 4)
                + (((((c4 >> 3) & 1) ^ (key4 >> 3)) & 1) << 3)
                + (c4 & 7);
            *(unsigned*)(Aband + boff) = u;
        }
    };

    if (iy == 0) {                            // row r=0 is ny=-1: zero 16KB
        for (int z = tid; z < 1024; z += 512) {
            uint4 zz; zz.x = 0u; zz.y = 0u; zz.z = 0u; zz.w = 0u;
            *(uint4*)(Aband + z * 16) = zz;
        }
    }
    {
        float4 fA[8], fB[8];
        const int r0 = (iy == 0) ? 1 : 0;
        issueRow(r0, fA);
        issueRow(r0 + 1, fB);
        writeRow(r0, fA);
        issueRow(2, fA);                      // r2 always valid (ny <= 127)
        writeRow(r0 + 1, fB);
        writeRow(2, fA);                      // when iy==0 this rewrites r2 (benign)
    }
    LOADB(0, bA);                             // tap-0 fragments fly under the sync
    __syncthreads();                          // band visible to all waves

    v16f acc[2];
#pragma unroll
    for (int j = 0; j < 2; j++) acc[j] = (v16f)(0.0f);

    auto computeTap = [&](const long long* buf, int dy, int dx) {
        const int r   = dy + 1;                          // band row, uniform
        const int ixv = wm + l31;                        // 0..63 output x
        const int nxq = (ixv << 1) + dx;                 // -1..127 input x
        const bool pad = (nxq < 0);
        const int nxs = pad ? 0 : nxq;
        const int key4 = ((nxq + 1) >> 1) & 15;
        const int abase = ((r * 128 + nxs) << 7) + ((hh ^ (key4 >> 3)) << 3);
        const int kc = key4 & 7;
#pragma unroll
        for (int seg = 0; seg < 8; ++seg) {   // K=128 -> 8 x (32x32x16)
            long long a0 = *(const long long*)(Aband + abase + ((seg ^ kc) << 4));
            if (pad) a0 = 0LL;
            __builtin_amdgcn_s_setprio(1);
#pragma unroll
            for (int j = 0; j < 2; j++)
                acc[j] = __builtin_amdgcn_mfma_f32_32x32x16_fp8_fp8(
                    a0, buf[(j << 3) + seg], acc[j], 0, 0, 0);
            __builtin_amdgcn_s_setprio(0);
        }
    };

    // ---- 9 taps, no barriers: load t+1 fragments while computing t ----
    LOADB(1, bB); computeTap(bA, -1, -1);     // tap0
    LOADB(2, bA); computeTap(bB, -1,  0);     // tap1
    LOADB(3, bB); computeTap(bA, -1,  1);     // tap2
    LOADB(4, bA); computeTap(bB,  0, -1);     // tap3
    LOADB(5, bB); computeTap(bA,  0,  0);     // tap4
    LOADB(6, bA); computeTap(bB,  0,  1);     // tap5
    LOADB(7, bB); computeTap(bA,  1, -1);     // tap6
    LOADB(8, bA); computeTap(bB,  1,  0);     // tap7
    computeTap(bA,  1,  1);                   // tap8

    // epilogue: 32x32 D layout col=lane&31, row=(reg&3)+8*(reg>>2)+4*(lane>>5)  [m74/m101]
    // nt stores: output stream does not allocate/thrash L2.
#pragma unroll
    for (int j = 0; j < 2; j++) {
        const int gcol = wn + (j << 5) + l31;
#pragma unroll
        for (int r = 0; r < 16; ++r) {
            const int grow = m0 + wm + (r & 3) + ((r >> 2) << 3) + (hh << 2);
            __builtin_nontemporal_store(acc[j][r], &out[(size_t)grow * 256 + gcol]);
        }
    }
#undef LOADB
}

// ---- fallback: direct fp32 conv ----
__global__ void naive_conv_kernel(const float* __restrict__ feats,
                                  const float* __restrict__ w,
                                  float* __restrict__ out) {
    int m = blockIdx.x;
    int n = threadIdx.x;
    int bb = m >> 12, iy = (m >> 6) & 63, ix = m & 63;
    float acc = 0.f;
    for (int tap = 0; tap < 9; ++tap) {
        int ny = 2 * iy + tap / 3 - 1;
        int nx = 2 * ix + tap % 3 - 1;
        if ((unsigned)ny < 128u && (unsigned)nx < 128u) {
            const float* fr = feats + ((size_t)((bb << 14) + (ny << 7) + nx) << 7);
            const float* wr = w + tap * 32768 + n;
            for (int c = 0; c < 128; ++c) acc += fr[c] * wr[c * 256];
        }
    }
    out[(size_t)m * 256 + n] = acc;
}

extern "C" void kernel_launch(void* const* d_in, const int* in_sizes, int n_in,
                              void* d_out, int out_size, void* d_ws, size_t ws_size,
                              hipStream_t stream) {
    const float* feats  = (const float*)d_in[0];
    const float* weight = (const float*)d_in[1];
    const float* alpha  = (const float*)d_in[2];
    float* out = (float*)d_out;

    const size_t NEED = (size_t)BW2_BYTES;
    if (ws_size >= NEED) {
        unsigned char* Bw2 = (unsigned char*)d_ws;
        wprep_kernel<<<144, 256, 0, stream>>>(weight, alpha, Bw2, out);
        gemm_conv_kernel<<<512, 512, 0, stream>>>(feats, Bw2, out);
    } else {
        coords_alpha_kernel<<<128, 256, 0, stream>>>(out, alpha);
        naive_conv_kernel<<<32768, 256, 0, stream>>>(feats, weight, out);
    }
}

// Round 13
// 127.732 us; speedup vs baseline: 1.1826x; 1.1826x over previous
//
#include <hip/hip_runtime.h>

// B=8, H=W=128, Cin=128, Cout=256, 3x3 stride2 pad1 -> OH=OW=64.
// Implicit GEMM: M=32768, N=256, K=1152 (9 taps x 128).
// d_out (f32): out_feats[32768*256] | out_coords[32768*3] | alpha[1]
// R20 = FINAL: revert to R16/R18 (best measured: total 128.1-128.7us, gemm
//      <=41.6us). R19's barrier-free register-B regressed (lost LDS broadcast:
//      per-CU B traffic 4x, gemm 57us). Structure: fused fp32->fp8 band
//      conversion in-kernel (no F8 intermediate), 2 blocks/CU (m-tile 64 =
//      one output row, full N=256), LDS = 48KB A-band + 32KB single-buffer B
//      = 80KB, 4-bit bank swizzle on A+B, per-tap global_load_lds B staging,
//      fp8 32x32x16 MFMA, nt epilogue stores, XCD-aware batch ownership.

#define OUT_FEATS_ELEMS (32768 * 256)
#define OUT_COORDS_OFF  OUT_FEATS_ELEMS
#define ALPHA_OFF       (OUT_FEATS_ELEMS + 32768 * 3)

#define BW_BYTES   (18 * 16384)

typedef float v16f __attribute__((ext_vector_type(16)));

__device__ __forceinline__ unsigned pk4fp8(float a, float b, float c, float d) {
    unsigned u = 0;
    u = __builtin_amdgcn_cvt_pk_fp8_f32(a, b, u, false);  // bytes 0,1
    u = __builtin_amdgcn_cvt_pk_fp8_f32(c, d, u, true);   // bytes 2,3
    return u;
}

#define GLOAD_LDS16(SRC, DST)                                                  \
    __builtin_amdgcn_global_load_lds(                                          \
        (const __attribute__((address_space(1))) void*)(SRC),                  \
        (__attribute__((address_space(3))) void*)(DST), 16, 0, 0)

#define WAITBAR_(N) asm volatile("s_waitcnt vmcnt(" #N ")\n\ts_barrier" ::: "memory")
#define WAITBAR(N)  WAITBAR_(N)
#define BAR()       asm volatile("s_barrier" ::: "memory")

// ---- weight prep: pre-swizzled fp8 B images + coords + alpha ----
// Image[t=nb*9+tap][row 0..127][phys chunk 0..7] (16B):
//   logical chunk (ch^(row&7)); 8B halves swapped when ((row>>3)&1).
__global__ void wprep_kernel(const float* __restrict__ w,
                             const float* __restrict__ alpha,
                             unsigned char* __restrict__ Bw,
                             float* __restrict__ out) {
    int cid = blockIdx.x * 256 + threadIdx.x;     // 0..36863
    if (cid < 32768) {                            // coords
        int b = cid >> 12, iy = (cid >> 6) & 63, ix = cid & 63;
        float* c = out + OUT_COORDS_OFF + (size_t)cid * 3;
        c[0] = (float)b; c[1] = (float)iy; c[2] = (float)ix;
        if (cid == 0) out[ALPHA_OFF] = alpha[0];
    }
    if (cid < 18432) {                            // 18 images x 128 rows x 8 chunks
        int ch  = cid & 7;
        int row = (cid >> 3) & 127;
        int t   = cid >> 10;                      // 0..17 = nb*9 + tap
        int nb  = (t >= 9) ? 1 : 0;
        int tap = t - 9 * nb;
        int chp = ch ^ (row & 7);
        int hb  = (row >> 3) & 1;
        int n   = (nb << 7) + row;
        int kb  = (tap << 7) + (chp << 4);
        unsigned u[4];
#pragma unroll
        for (int q = 0; q < 4; ++q) {
            int kq = kb + 4 * (q ^ (hb << 1));    // half-swap when hb=1
            float f0 = w[(size_t)(kq + 0) * 256 + n];
            float f1 = w[(size_t)(kq + 1) * 256 + n];
            float f2 = w[(size_t)(kq + 2) * 256 + n];
            float f3 = w[(size_t)(kq + 3) * 256 + n];
            u[q] = pk4fp8(f0, f1, f2, f3);
        }
        uint4 r; r.x = u[0]; r.y = u[1]; r.z = u[2]; r.w = u[3];
        *(uint4*)(Bw + (size_t)cid * 16) = r;
    }
}

// ---- coords for fallback path ----
__global__ void coords_alpha_kernel(float* __restrict__ out, const float* __restrict__ alpha) {
    int i = blockIdx.x * 256 + threadIdx.x;
    int b = i >> 12, iy = (i >> 6) & 63, ix = i & 63;
    float* c = out + OUT_COORDS_OFF + (size_t)i * 3;
    c[0] = (float)b; c[1] = (float)iy; c[2] = (float)ix;
    if (i == 0) out[ALPHA_OFF] = alpha[0];
}

// ---- fused conv GEMM, 2 blocks/CU ----
// Aband: [r 0..2][nx 0..127][128B]. key4=((nx+1)>>1)&15. logical chunk c half h
//   stored at phys chunk c^(key4&7), half h^(key4>>3). r = ny - (2*iy - 1).
//   nx=-1 handled by register predicate (a0=0). Row r=0 zeroed when iy==0.
__global__ __launch_bounds__(512, 4) void gemm_conv_kernel(
    const float* __restrict__ feats,         // fp32 [B*128*128][128]
    const unsigned char* __restrict__ Bw,    // pre-swizzled fp8 B images (18 x 16KB)
    float* __restrict__ out)                 // [32768][256]
{
    __shared__ unsigned char Aband[3 * 128 * 128];   // 49,152 B
    __shared__ unsigned char Bs[256 * 128];          // 32,768 B  (80KB total)

    const int tid  = threadIdx.x;
    const int bid  = blockIdx.x;             // 0..511
    // XCD-aware: XCD (bid&7) owns batch bb=(bid&7).
    const int my   = ((bid & 7) << 6) + ((bid >> 3) & 63);   // 0..511
    const int m0   = my << 6;
    const int bb   = my >> 6;                // == bid & 7
    const int iy   = my & 63;                // this block's single output row

    const int lane = tid & 63, wave = tid >> 6;  // wave 0..7
    const int wm   = (wave >> 2) << 5;       // 0 / 32   (m within tile)
    const int wn   = (wave & 3) << 6;        // 0 / 64 / 128 / 192
    const int l31  = lane & 31;
    const int hh   = lane >> 5;              // k-half select
    const int xorl = l31 & 7;
    const int bhalf = (hh ^ ((l31 >> 3) & 1)) << 3;   // B phys 8B-half offset

    // ---- B staging (4 x global_load_lds per wave per tap; single buffer) ----
    const unsigned char* bsrc0 = Bw + ((size_t)((wave >> 2) * 9) << 14)
                                    + ((size_t)(wave & 3) << 12) + ((size_t)lane << 4);
    auto stageB = [&](int tap) {
        const unsigned char* bs = bsrc0 + ((size_t)tap << 14);
        unsigned char* bdst = Bs + (wave << 12);
#pragma unroll
        for (int q = 0; q < 4; ++q)
            GLOAD_LDS16(bs + (q << 10), bdst + (q << 10));
    };

    stageB(0);                                // overlap tap-0 B DMA with band phase

    // ---- band fill: 3 input rows (ny = 2*iy-1 .. 2*iy+1), fp32 -> fp8 ----
    const int ny0 = (iy << 1) - 1;
    auto issueRow = [&](int r, float4* f) {
        const int ny = ny0 + r;
#pragma unroll
        for (int it = 0; it < 8; ++it) {
            const int idx = (it << 9) + tid;      // 0..4095
            const int nx  = idx >> 5;
            const int c4  = (idx & 31) << 2;      // float index 0..124 step 4
            f[it] = *(const float4*)(feats +
                ((((size_t)(bb << 14) + ny * 128 + nx)) << 7) + c4);
        }
    };
    auto writeRow = [&](int r, const float4* f) {
#pragma unroll
        for (int it = 0; it < 8; ++it) {
            const int idx = (it << 9) + tid;
            const int nx  = idx >> 5;
            const int c4  = (idx & 31) << 2;
            const unsigned u = pk4fp8(f[it].x, f[it].y, f[it].z, f[it].w);
            const int key4 = ((nx + 1) >> 1) & 15;
            const int boff = ((r * 128 + nx) << 7)
                + (((c4 >> 4) ^ (key4 & 7)) << 4)
                + (((((c4 >> 3) & 1) ^ (key4 >> 3)) & 1) << 3)
                + (c4 & 7);
            *(unsigned*)(Aband + boff) = u;
        }
    };

    if (iy == 0) {                            // row r=0 is ny=-1: zero 16KB
        for (int z = tid; z < 1024; z += 512) {
            uint4 zz; zz.x = 0u; zz.y = 0u; zz.z = 0u; zz.w = 0u;
            *(uint4*)(Aband + z * 16) = zz;
        }
    }
    {
        float4 fA[8], fB[8];
        const int r0 = (iy == 0) ? 1 : 0;
        issueRow(r0, fA);
        issueRow(r0 + 1, fB);
        writeRow(r0, fA);
        issueRow(2, fA);                      // r2 always valid (ny <= 127)
        writeRow(r0 + 1, fB);
        writeRow(2, fA);                      // when iy==0 this rewrites r2 (benign)
    }
    __syncthreads();                          // band + B(0) visible (full drain)

    v16f acc[2];
#pragma unroll
    for (int j = 0; j < 2; j++) acc[j] = (v16f)(0.0f);

    auto computeTap = [&](int dy, int dx) {
        const int r   = dy + 1;                          // band row, uniform
        const int ixv = wm + l31;                        // 0..63 output x
        const int nxq = (ixv << 1) + dx;                 // -1..127 input x
        const bool pad = (nxq < 0);
        const int nxs = pad ? 0 : nxq;
        const int key4 = ((nxq + 1) >> 1) & 15;
        const int abase = ((r * 128 + nxs) << 7) + ((hh ^ (key4 >> 3)) << 3);
        const int kc = key4 & 7;
#pragma unroll
        for (int seg = 0; seg < 8; ++seg) {   // K=128 -> 8 x (32x32x16)
            long long a0 = *(const long long*)(Aband + abase + ((seg ^ kc) << 4));
            if (pad) a0 = 0LL;
            long long b2[2];
#pragma unroll
            for (int j = 0; j < 2; j++)
                b2[j] = *(const long long*)(Bs + ((wn + (j << 5) + l31) << 7)
                                            + ((seg ^ xorl) << 4) + bhalf);
            __builtin_amdgcn_s_setprio(1);
#pragma unroll
            for (int j = 0; j < 2; j++)
                acc[j] = __builtin_amdgcn_mfma_f32_32x32x16_fp8_fp8(a0, b2[j], acc[j], 0, 0, 0);
            __builtin_amdgcn_s_setprio(0);
        }
    };

#pragma unroll
    for (int tap = 0; tap < 9; ++tap) {
        computeTap(tap / 3 - 1, tap % 3 - 1);
        if (tap < 8) {
            BAR();                            // all waves done reading Bs
            stageB(tap + 1);
            WAITBAR(0);                       // stage complete before next compute
        }
    }

    // epilogue: 32x32 D layout col=lane&31, row=(reg&3)+8*(reg>>2)+4*(lane>>5)  [m74/m101]
    // nt stores: output stream does not allocate/thrash L2.
#pragma unroll
    for (int j = 0; j < 2; j++) {
        const int gcol = wn + (j << 5) + l31;
#pragma unroll
        for (int r = 0; r < 16; ++r) {
            const int grow = m0 + wm + (r & 3) + ((r >> 2) << 3) + (hh << 2);
            __builtin_nontemporal_store(acc[j][r], &out[(size_t)grow * 256 + gcol]);
        }
    }
}

// ---- fallback: direct fp32 conv ----
__global__ void naive_conv_kernel(const float* __restrict__ feats,
                                  const float* __restrict__ w,
                                  float* __restrict__ out) {
    int m = blockIdx.x;
    int n = threadIdx.x;
    int bb = m >> 12, iy = (m >> 6) & 63, ix = m & 63;
    float acc = 0.f;
    for (int tap = 0; tap < 9; ++tap) {
        int ny = 2 * iy + tap / 3 - 1;
        int nx = 2 * ix + tap % 3 - 1;
        if ((unsigned)ny < 128u && (unsigned)nx < 128u) {
            const float* fr = feats + ((size_t)((bb << 14) + (ny << 7) + nx) << 7);
            const float* wr = w + tap * 32768 + n;
            for (int c = 0; c < 128; ++c) acc += fr[c] * wr[c * 256];
        }
    }
    out[(size_t)m * 256 + n] = acc;
}

extern "C" void kernel_launch(void* const* d_in, const int* in_sizes, int n_in,
                              void* d_out, int out_size, void* d_ws, size_t ws_size,
                              hipStream_t stream) {
    const float* feats  = (const float*)d_in[0];
    const float* weight = (const float*)d_in[1];
    const float* alpha  = (const float*)d_in[2];
    float* out = (float*)d_out;

    const size_t NEED = (size_t)BW_BYTES;
    if (ws_size >= NEED) {
        unsigned char* Bw = (unsigned char*)d_ws;
        wprep_kernel<<<144, 256, 0, stream>>>(weight, alpha, Bw, out);
        gemm_conv_kernel<<<512, 512, 0, stream>>>(feats, Bw, out);
    } else {
        coords_alpha_kernel<<<128, 256, 0, stream>>>(out, alpha);
        naive_conv_kernel<<<32768, 256, 0, stream>>>(feats, weight, out);
    }
}